// Round 19
// baseline (286.098 us; speedup 1.0000x reference)
//
#include <hip/hip_runtime.h>
#include <math.h>

#define NN 500
#define TT 48
#define NT 24000   // NN*TT
#define NF4 6000   // NT/4

typedef float f4v __attribute__((ext_vector_type(4)));

// ---------- kernel 0a: row sums of s ----------
__global__ void k_srow(const float* __restrict__ s, float* __restrict__ srow) {
    int r = blockIdx.x;
    int l = threadIdx.x;
    float v = 0.f;
    for (int j = l; j < NN; j += 64) v += s[r * NN + j];
    #pragma unroll
    for (int o = 32; o; o >>= 1) v += __shfl_xor(v, o);
    if (l == 0) srow[r] = v;
}

// ---------- kernel 1: k_bw-SHAPED softmax fold ----------
// 2048 blocks x 256 thr; each block streams TWO CONSECUTIVE bc rows (3 MB
// contiguous) with f = i*256 + tid strided loads — the exact access shape the
// r9/r11 probes measured at ~7.8 TB/s. Two-level softmax: per-f4 (sf, ml) in
// regs, block max M, rescale, LDS p[f] fold, per-node gather (EACH THREAD
// GATHERS TWO NODES — r18 bug: only tid<256 gathered, leaving nodes 256..499
// poisoned), block Z, direct normalization.
__launch_bounds__(256, 4)
__global__ void k_p1(const float* __restrict__ x, const float* __restrict__ srow,
                     float* __restrict__ xws) {
    __shared__ __align__(16) float p[6144];   // per-f4 contributions (f-indexed)
    __shared__ __align__(16) float sr[512];   // srow staged (500 used)
    __shared__ float red[8];
    int g = blockIdx.x;                       // 0..2047
    int tid = threadIdx.x;
    int w = tid >> 6, l = tid & 63;

    sr[tid] = srow[(tid < NN) ? tid : (NN - 1)];
    int t2 = tid + 256;
    sr[t2] = (t2 < NN) ? srow[t2] : 0.f;
    __syncthreads();

    #pragma unroll 1
    for (int rr = 0; rr < 2; ++rr) {
        int bc = g * 2 + rr;                  // two consecutive rows per block
        const f4v* xp = (const f4v*)x + (size_t)bc * NF4;

        float sf[24], ml[24];
        float m = 0.f;                        // relu >= 0 -> 0 is safe identity
        #pragma unroll
        for (int i = 0; i < 24; i++) {
            int f = i * 256 + tid;
            int fc = (f < NF4) ? f : (NF4 - 1);   // only i==23 can exceed
            float msk = (f < NF4) ? 1.f : 0.f;
            f4v xv = xp[fc];
            int kk = 4 * fc;
            int ti = kk / 500;                // magic-mul div
            int v  = kk - ti * 500;           // multiple of 4 -> aligned f4
            float tt = (float)(TT - 1 - ti) * 0.8f;
            float4 sv = *(const float4*)(sr + v);
            float y0 = fmaxf(xv.x * (tt + sv.x) * 0.125f, 0.f);
            float y1 = fmaxf(xv.y * (tt + sv.y) * 0.125f, 0.f);
            float y2 = fmaxf(xv.z * (tt + sv.z) * 0.125f, 0.f);
            float y3 = fmaxf(xv.w * (tt + sv.w) * 0.125f, 0.f);
            float mm = fmaxf(fmaxf(y0, y1), fmaxf(y2, y3));
            float sfi = __expf(y0 - mm) + __expf(y1 - mm)
                      + __expf(y2 - mm) + __expf(y3 - mm);
            sf[i] = sfi * msk;
            ml[i] = mm;                       // clamped dup echoes a real element
            m = fmaxf(m, mm);
        }

        // block max M
        #pragma unroll
        for (int o = 32; o; o >>= 1) m = fmaxf(m, __shfl_xor(m, o));
        if (l == 0) red[w] = m;
        __syncthreads();
        float M = fmaxf(fmaxf(red[0], red[1]), fmaxf(red[2], red[3]));

        // rescale to M, scatter to p[f] (2-way bank alias = free), thread total
        float tot = 0.f;
        #pragma unroll
        for (int i = 0; i < 24; i++) {
            float cf = sf[i] * __expf(ml[i] - M);
            p[i * 256 + tid] = cf;
            tot += cf;
        }
        #pragma unroll
        for (int o = 32; o; o >>= 1) tot += __shfl_xor(tot, o);
        if (l == 0) red[4 + w] = tot;
        __syncthreads();                      // p visible + red[4..7] ready
        float Z = (red[4] + red[5]) + (red[6] + red[7]);
        float invZ = 1.f / Z;

        // node gather: thread handles nodes tid and tid+256 (500 total)
        #pragma unroll
        for (int q = 0; q < 2; ++q) {
            int n = tid + q * 256;
            if (n < NN) {
                const float4* pp = (const float4*)(p + n * 12);   // 48B-aligned
                float4 a = pp[0], b4 = pp[1], c4 = pp[2];
                float sn = a.x + a.y + a.z + a.w + b4.x + b4.y + b4.z + b4.w
                         + c4.x + c4.y + c4.z + c4.w;
                xws[(size_t)bc * NN + n] = sn * invZ;
            }
        }
        __syncthreads();                      // protect p/red before next row
    }
}

// ---------- kernel 2: gram (X^T X over C=64) fused with row softmax ----------
// xws fully normalized in p1; proven r3 structure.
__launch_bounds__(512, 2)
__global__ void k_p2(const float* __restrict__ xws, float* __restrict__ out) {
    __shared__ __align__(16) float Xs[32 * NN + 16];
    int b = blockIdx.y;
    int rt8 = blockIdx.x;   // 0..7
    int tid = threadIdx.x;

    int rt = tid >> 6, cx = tid & 63;
    int r0 = rt8 * 64 + rt * 8;
    int cb0 = cx * 4, cb1 = cx * 4 + 256;

    float acc[8][8];
    #pragma unroll
    for (int i = 0; i < 8; i++)
        #pragma unroll
        for (int j = 0; j < 8; j++) acc[i][j] = 0.f;

    for (int cbk = 0; cbk < 2; cbk++) {
        const float4* src4 = (const float4*)(xws + ((size_t)b * 64 + 32 * cbk) * NN);
        __syncthreads();                 // protect previous Xs use
        #pragma unroll
        for (int i = 0; i < 8; i++) {
            int idx = tid + i * 512;
            if (idx < 4000) ((float4*)Xs)[idx] = src4[idx];
        }
        if (tid < 16) Xs[32 * NN + tid] = 0.f;   // zero the guard pad
        __syncthreads();

        #pragma unroll 4
        for (int c = 0; c < 32; c++) {
            const float* row = Xs + c * NN;
            float4 a0 = *(const float4*)(row + r0);       // broadcast (uniform addr)
            float4 a1 = *(const float4*)(row + r0 + 4);
            float4 b0 = *(const float4*)(row + cb0);      // lanes contiguous 16B
            float4 b1 = *(const float4*)(row + cb1);
            float av[8] = {a0.x, a0.y, a0.z, a0.w, a1.x, a1.y, a1.z, a1.w};
            float bv[8] = {b0.x, b0.y, b0.z, b0.w, b1.x, b1.y, b1.z, b1.w};
            #pragma unroll
            for (int i = 0; i < 8; i++)
                #pragma unroll
                for (int j = 0; j < 8; j++)
                    acc[i][j] = fmaf(av[i], bv[j], acc[i][j]);
        }
    }

    bool c1v = (cx <= 60);
    size_t ob = (size_t)b * (NN * NN);
    #pragma unroll 1
    for (int ri = 0; ri < 8; ri++) {
        int r = r0 + ri;
        if (r >= NN) break;         // wave-uniform
        float u[8];
        #pragma unroll
        for (int j = 0; j < 8; j++) u[j] = fmaxf(acc[ri][j], 0.f) * 0.125f;
        float mx = fmaxf(fmaxf(u[0], u[1]), fmaxf(u[2], u[3]));
        if (c1v) mx = fmaxf(mx, fmaxf(fmaxf(u[4], u[5]), fmaxf(u[6], u[7])));
        #pragma unroll
        for (int o = 32; o; o >>= 1) mx = fmaxf(mx, __shfl_xor(mx, o));

        float e[8];
        float es = 0.f;
        #pragma unroll
        for (int j = 0; j < 4; j++) { e[j] = __expf(u[j] - mx); es += e[j]; }
        if (c1v) {
            #pragma unroll
            for (int j = 4; j < 8; j++) { e[j] = __expf(u[j] - mx); es += e[j]; }
        }
        #pragma unroll
        for (int o = 32; o; o >>= 1) es += __shfl_xor(es, o);
        float inv = 1.f / es;

        float4 w0 = make_float4(e[0] * inv, e[1] * inv, e[2] * inv, e[3] * inv);
        *(float4*)(out + ob + (size_t)r * NN + cb0) = w0;
        if (c1v) {
            float4 w1 = make_float4(e[4] * inv, e[5] * inv, e[6] * inv, e[7] * inv);
            *(float4*)(out + ob + (size_t)r * NN + cb1) = w1;
        }
    }
}

extern "C" void kernel_launch(void* const* d_in, const int* in_sizes, int n_in,
                              void* d_out, int out_size, void* d_ws, size_t ws_size,
                              hipStream_t stream) {
    const float* x = (const float*)d_in[0];   // [64,64,500,48]
    const float* s = (const float*)d_in[1];   // [500,500]
    float* out = (float*)d_out;               // [64,500,500]
    float* wsf = (float*)d_ws;

    float* srow = wsf;             // 500 floats
    float* xws  = wsf + 32768;     // 64*64*500 = 2,048,000 floats (~8.2 MB)

    k_srow<<<NN, 64, 0, stream>>>(s, srow);
    k_p1<<<2048, 256, 0, stream>>>(x, srow, xws);
    dim3 g2(8, 64);
    k_p2<<<g2, 512, 0, stream>>>(xws, out);
}

// Round 20
// 165.824 us; speedup vs baseline: 1.7253x; 1.7253x over previous
//
#include <hip/hip_runtime.h>
#include <math.h>

#define NN 500
#define TT 48
#define NT 24000   // NN*TT
#define NF4 6000   // NT/4

typedef float f4v __attribute__((ext_vector_type(4)));

// ---------- kernel 0a: row sums of s ----------
__global__ void k_srow(const float* __restrict__ s, float* __restrict__ srow) {
    int r = blockIdx.x;
    int l = threadIdx.x;
    float v = 0.f;
    for (int j = l; j < NN; j += 64) v += s[r * NN + j];
    #pragma unroll
    for (int o = 32; o; o >>= 1) v += __shfl_xor(v, o);
    if (l == 0) srow[r] = v;
}

// ---------- kernel 1: k_bw-shaped softmax fold, LDS-resident state ----------
// r19 counters: VGPR=64 with sf[24]+ml[24] live -> compiler spilled to
// scratch (WRITE 182 MB vs 8 MB demand; VALUBusy 13.8%; latency-bound;
// t_p1=234us). Fix: the per-f4 (sf, ml) state lives in LDS (p[6144] +
// mla[6144], 51 KB, 3 blocks/CU), register footprint ~35 -> no spill.
// Phase 1: stream 24 f4/thread (k_bw sequential-contiguous shape), write
// (sfi, mm) to LDS, thread max. Phase 2: block max M; each thread rescales
// its own 24 entries (cf = sf*exp(ml-M)) in place, accumulates Z.
// Phase 3: gather 2 nodes/thread (r18 fix), normalize, store.
__launch_bounds__(256, 4)
__global__ void k_p1(const float* __restrict__ x, const float* __restrict__ srow,
                     float* __restrict__ xws) {
    __shared__ __align__(16) float p[6144];    // per-f4 exp-sums -> rescaled cf
    __shared__ __align__(16) float mla[6144];  // per-f4 local maxima
    __shared__ __align__(16) float sr[512];    // srow staged (500 used)
    __shared__ float red[8];
    int g = blockIdx.x;                        // 0..2047
    int tid = threadIdx.x;
    int w = tid >> 6, l = tid & 63;

    sr[tid] = srow[(tid < NN) ? tid : (NN - 1)];
    int t2 = tid + 256;
    sr[t2] = (t2 < NN) ? srow[t2] : 0.f;
    __syncthreads();

    #pragma unroll 1
    for (int rr = 0; rr < 2; ++rr) {
        int bc = g * 2 + rr;                   // two consecutive rows per block
        const f4v* xp = (const f4v*)x + (size_t)bc * NF4;

        // ---- phase 1: stream + per-f4 (sfi, mm) -> LDS ----
        float m = 0.f;                         // relu >= 0 -> 0 is safe identity
        #pragma unroll
        for (int i = 0; i < 24; i++) {
            int f = i * 256 + tid;
            int fc = (f < NF4) ? f : (NF4 - 1);    // only i==23 can exceed
            float msk = (f < NF4) ? 1.f : 0.f;
            f4v xv = xp[fc];
            int kk = 4 * fc;
            int ti = kk / 500;                 // magic-mul div
            int v  = kk - ti * 500;            // multiple of 4 -> aligned f4
            float tt = (float)(TT - 1 - ti) * 0.8f;
            float4 sv = *(const float4*)(sr + v);
            float y0 = fmaxf(xv.x * (tt + sv.x) * 0.125f, 0.f);
            float y1 = fmaxf(xv.y * (tt + sv.y) * 0.125f, 0.f);
            float y2 = fmaxf(xv.z * (tt + sv.z) * 0.125f, 0.f);
            float y3 = fmaxf(xv.w * (tt + sv.w) * 0.125f, 0.f);
            float mm = fmaxf(fmaxf(y0, y1), fmaxf(y2, y3));
            float sfi = __expf(y0 - mm) + __expf(y1 - mm)
                      + __expf(y2 - mm) + __expf(y3 - mm);
            int idx = i * 256 + tid;           // stride-256 scatter: conflict-free
            p[idx]   = sfi * msk;              // clamped dup masked to 0
            mla[idx] = mm;                     // dup echoes a real element: safe in max
            m = fmaxf(m, mm);
        }

        // ---- block max M ----
        #pragma unroll
        for (int o = 32; o; o >>= 1) m = fmaxf(m, __shfl_xor(m, o));
        if (l == 0) red[w] = m;
        __syncthreads();
        float M = fmaxf(fmaxf(red[0], red[1]), fmaxf(red[2], red[3]));

        // ---- phase 2: rescale own entries in place, accumulate Z ----
        float tot = 0.f;
        #pragma unroll
        for (int i = 0; i < 24; i++) {
            int idx = i * 256 + tid;
            float cf = p[idx] * __expf(mla[idx] - M);
            p[idx] = cf;
            tot += cf;
        }
        #pragma unroll
        for (int o = 32; o; o >>= 1) tot += __shfl_xor(tot, o);
        if (l == 0) red[4 + w] = tot;
        __syncthreads();                       // cf visible + red[4..7] ready
        float Z = (red[4] + red[5]) + (red[6] + red[7]);
        float invZ = 1.f / Z;

        // ---- phase 3: gather 2 nodes/thread (covers all 500), normalize ----
        #pragma unroll
        for (int q = 0; q < 2; ++q) {
            int n = tid + q * 256;
            if (n < NN) {
                const float4* pp = (const float4*)(p + n * 12);   // 48B-aligned
                float4 a = pp[0], b4 = pp[1], c4 = pp[2];
                float sn = a.x + a.y + a.z + a.w + b4.x + b4.y + b4.z + b4.w
                         + c4.x + c4.y + c4.z + c4.w;
                xws[(size_t)bc * NN + n] = sn * invZ;
            }
        }
        __syncthreads();                       // protect p/mla/red before next row
    }
}

// ---------- kernel 2: gram (X^T X over C=64) fused with row softmax ----------
// xws fully normalized in p1; proven r3 structure at (512,4) — the config the
// r4 probe timed at ~38 us.
__launch_bounds__(512, 4)
__global__ void k_p2(const float* __restrict__ xws, float* __restrict__ out) {
    __shared__ __align__(16) float Xs[32 * NN + 16];
    int b = blockIdx.y;
    int rt8 = blockIdx.x;   // 0..7
    int tid = threadIdx.x;

    int rt = tid >> 6, cx = tid & 63;
    int r0 = rt8 * 64 + rt * 8;
    int cb0 = cx * 4, cb1 = cx * 4 + 256;

    float acc[8][8];
    #pragma unroll
    for (int i = 0; i < 8; i++)
        #pragma unroll
        for (int j = 0; j < 8; j++) acc[i][j] = 0.f;

    for (int cbk = 0; cbk < 2; cbk++) {
        const float4* src4 = (const float4*)(xws + ((size_t)b * 64 + 32 * cbk) * NN);
        __syncthreads();                 // protect previous Xs use
        #pragma unroll
        for (int i = 0; i < 8; i++) {
            int idx = tid + i * 512;
            if (idx < 4000) ((float4*)Xs)[idx] = src4[idx];
        }
        if (tid < 16) Xs[32 * NN + tid] = 0.f;   // zero the guard pad
        __syncthreads();

        #pragma unroll 4
        for (int c = 0; c < 32; c++) {
            const float* row = Xs + c * NN;
            float4 a0 = *(const float4*)(row + r0);       // broadcast (uniform addr)
            float4 a1 = *(const float4*)(row + r0 + 4);
            float4 b0 = *(const float4*)(row + cb0);      // lanes contiguous 16B
            float4 b1 = *(const float4*)(row + cb1);
            float av[8] = {a0.x, a0.y, a0.z, a0.w, a1.x, a1.y, a1.z, a1.w};
            float bv[8] = {b0.x, b0.y, b0.z, b0.w, b1.x, b1.y, b1.z, b1.w};
            #pragma unroll
            for (int i = 0; i < 8; i++)
                #pragma unroll
                for (int j = 0; j < 8; j++)
                    acc[i][j] = fmaf(av[i], bv[j], acc[i][j]);
        }
    }

    bool c1v = (cx <= 60);
    size_t ob = (size_t)b * (NN * NN);
    #pragma unroll 1
    for (int ri = 0; ri < 8; ri++) {
        int r = r0 + ri;
        if (r >= NN) break;         // wave-uniform
        float u[8];
        #pragma unroll
        for (int j = 0; j < 8; j++) u[j] = fmaxf(acc[ri][j], 0.f) * 0.125f;
        float mx = fmaxf(fmaxf(u[0], u[1]), fmaxf(u[2], u[3]));
        if (c1v) mx = fmaxf(mx, fmaxf(fmaxf(u[4], u[5]), fmaxf(u[6], u[7])));
        #pragma unroll
        for (int o = 32; o; o >>= 1) mx = fmaxf(mx, __shfl_xor(mx, o));

        float e[8];
        float es = 0.f;
        #pragma unroll
        for (int j = 0; j < 4; j++) { e[j] = __expf(u[j] - mx); es += e[j]; }
        if (c1v) {
            #pragma unroll
            for (int j = 4; j < 8; j++) { e[j] = __expf(u[j] - mx); es += e[j]; }
        }
        #pragma unroll
        for (int o = 32; o; o >>= 1) es += __shfl_xor(es, o);
        float inv = 1.f / es;

        float4 w0 = make_float4(e[0] * inv, e[1] * inv, e[2] * inv, e[3] * inv);
        *(float4*)(out + ob + (size_t)r * NN + cb0) = w0;
        if (c1v) {
            float4 w1 = make_float4(e[4] * inv, e[5] * inv, e[6] * inv, e[7] * inv);
            *(float4*)(out + ob + (size_t)r * NN + cb1) = w1;
        }
    }
}

extern "C" void kernel_launch(void* const* d_in, const int* in_sizes, int n_in,
                              void* d_out, int out_size, void* d_ws, size_t ws_size,
                              hipStream_t stream) {
    const float* x = (const float*)d_in[0];   // [64,64,500,48]
    const float* s = (const float*)d_in[1];   // [500,500]
    float* out = (float*)d_out;               // [64,500,500]
    float* wsf = (float*)d_ws;

    float* srow = wsf;             // 500 floats
    float* xws  = wsf + 32768;     // 64*64*500 = 2,048,000 floats (~8.2 MB)

    k_srow<<<NN, 64, 0, stream>>>(s, srow);
    k_p1<<<2048, 256, 0, stream>>>(x, srow, xws);
    dim3 g2(8, 64);
    k_p2<<<g2, 512, 0, stream>>>(xws, out);
}